// Round 16
// baseline (125.976 us; speedup 1.0000x reference)
//
#include <hip/hip_runtime.h>

#define SK 8192
#define SQ 8192
#define DD 128
#define ZSPLIT 8

typedef __attribute__((ext_vector_type(8))) short short8;
typedef __attribute__((ext_vector_type(4))) float f32x4;
typedef __attribute__((ext_vector_type(4))) unsigned uint4v;
typedef unsigned short ushort_t;

// round-to-nearest-even f32 -> bf16
__device__ __forceinline__ unsigned short f2bf(float x){
  unsigned int u = __float_as_uint(x);
  u += 0x7FFFu + ((u >> 16) & 1u);
  return (unsigned short)(u >> 16);
}

// async global->LDS DMA, 16B/lane. LDS dest = uniform base + lane*16.
__device__ __forceinline__ void gld16(const void* g, void* l){
  __builtin_amdgcn_global_load_lds(
      (const __attribute__((address_space(1))) unsigned int*)g,
      (__attribute__((address_space(3))) unsigned int*)l, 16, 0, 0);
}

// ---------------------------------------------------------------------------
// STREAM LAYOUTS (fragment-record form; all reads are coalesced 1KB records)
// K/Q stream: per 64-row tile, 16 records of 1KB; rec = rg*4 + kk.
//   Lane l, byte pair j: element M[tile*64 + rg*16 + (l&15)][kk*32 + (l>>4)*8 + j]
// V stream: per 64-q tile, 16 records; rec = qc*8 + dvb. Lane l:
//   element V^T[dvb*16 + (l&15)][qc*32 + (l>>4)*8 + j]  (V^T pre-scaled 1/Z)
// ---------------------------------------------------------------------------

// prep_kq: cast K (pre-scaled by log2(e)/sqrt(128)) and Q to bf16 streams.
__global__ __launch_bounds__(256) void prep_kq(const float* __restrict__ Kp,
                                               const float* __restrict__ Qp,
                                               ushort_t* __restrict__ kst,
                                               ushort_t* __restrict__ qst){
  int g = blockIdx.x*256 + threadIdx.x;
  int arr = g >> 17;
  int s   = g & 131071;
  int row = s >> 4;
  int c16 = s & 15;            // 8-elem slot: d = c16*8..c16*8+7
  const float* src = (arr ? Qp : Kp) + row*DD + c16*8;
  const float scale = arr ? 1.0f : 0.12751743f;   // log2(e)/sqrt(128)
  float4 f0 = ((const float4*)src)[0];
  float4 f1 = ((const float4*)src)[1];
  unsigned int wv[4];
  wv[0] = (unsigned)f2bf(f0.x*scale) | ((unsigned)f2bf(f0.y*scale) << 16);
  wv[1] = (unsigned)f2bf(f0.z*scale) | ((unsigned)f2bf(f0.w*scale) << 16);
  wv[2] = (unsigned)f2bf(f1.x*scale) | ((unsigned)f2bf(f1.y*scale) << 16);
  wv[3] = (unsigned)f2bf(f1.z*scale) | ((unsigned)f2bf(f1.w*scale) << 16);
  ushort_t* base = arr ? qst : kst;
  int tile = row >> 6, rg = (row >> 4) & 3, r15 = row & 15;
  int kk = c16 >> 2, g4 = c16 & 3;
  char* dst = (char*)base + (size_t)tile*16384 + (rg*4 + kk)*1024 + (g4*16 + r15)*16;
  ((uint4*)dst)[0] = make_uint4(wv[0],wv[1],wv[2],wv[3]);
}

// ---------------------------------------------------------------------------
// kz: per-column stats, BARRIER-FREE main loop (r14/r15, passing).
// ---------------------------------------------------------------------------
__global__ __launch_bounds__(256, 4) void kz(const ushort_t* __restrict__ kst,
                                             const ushort_t* __restrict__ qst,
                                             float* __restrict__ zpart){
  __shared__ __align__(16) float zred[256];
  int wg = blockIdx.x;            // 1024
  int qs   = wg >> 3;             // 0..127 (64-q stripe)
  int kspl = wg & 7;
  int t = threadIdx.x, lane = t & 63, w = t >> 6;   // w in 0..3

  short8 qf[4][4];
  { const char* qg = (const char*)qst + (size_t)qs*16384;
    #pragma unroll
    for (int qg_=0; qg_<4; ++qg_)
      #pragma unroll
      for (int kk=0; kk<4; ++kk)
        qf[qg_][kk] = *(const short8*)(qg + ((qg_*4+kk)<<10) + lane*16);
  }

  float zac0=0.f, zac1=0.f, zac2=0.f, zac3=0.f;
  const char* kbase = (const char*)kst + (size_t)(kspl*16)*16384 + ((w*4)<<10) + lane*16;
  for (int it=0; it<16; ++it){
    short8 ak[4];
    #pragma unroll
    for (int kk=0;kk<4;kk++)
      ak[kk] = *(const short8*)(kbase + (size_t)it*16384 + (kk<<10));
    f32x4 s0={0,0,0,0}, s1={0,0,0,0}, s2={0,0,0,0}, s3={0,0,0,0};
    #pragma unroll
    for (int kk=0; kk<4; ++kk){
      s0 = __builtin_amdgcn_mfma_f32_16x16x32_bf16(ak[kk], qf[0][kk], s0, 0, 0, 0);
      s1 = __builtin_amdgcn_mfma_f32_16x16x32_bf16(ak[kk], qf[1][kk], s1, 0, 0, 0);
      s2 = __builtin_amdgcn_mfma_f32_16x16x32_bf16(ak[kk], qf[2][kk], s2, 0, 0, 0);
      s3 = __builtin_amdgcn_mfma_f32_16x16x32_bf16(ak[kk], qf[3][kk], s3, 0, 0, 0);
    }
    #pragma unroll
    for (int j=0;j<4;j++){
      zac0 += __builtin_exp2f(s0[j]);
      zac1 += __builtin_exp2f(s1[j]);
      zac2 += __builtin_exp2f(s2[j]);
      zac3 += __builtin_exp2f(s3[j]);
    }
  }
  zac0 += __shfl_xor(zac0,16); zac0 += __shfl_xor(zac0,32);
  zac1 += __shfl_xor(zac1,16); zac1 += __shfl_xor(zac1,32);
  zac2 += __shfl_xor(zac2,16); zac2 += __shfl_xor(zac2,32);
  zac3 += __shfl_xor(zac3,16); zac3 += __shfl_xor(zac3,32);
  if (lane < 16){
    zred[w*64 + 0*16 + lane] = zac0;
    zred[w*64 + 1*16 + lane] = zac1;
    zred[w*64 + 2*16 + lane] = zac2;
    zred[w*64 + 3*16 + lane] = zac3;
  }
  __syncthreads();
  if (t < 64){
    float z = zred[t] + zred[64+t] + zred[128+t] + zred[192+t];
    zpart[(size_t)kspl*SQ + qs*64 + t] = z;
  }
}

// ---------------------------------------------------------------------------
// prep_v: runs AFTER kz. Vt[q,:] = V[q,:] / Z_q, written as V stream records.
// ---------------------------------------------------------------------------
__global__ __launch_bounds__(256) void prep_v(const float* __restrict__ Vp,
                                              const float* __restrict__ zpart,
                                              ushort_t* __restrict__ vst){
  __shared__ ushort_t vl[64][132];
  int tile = blockIdx.x;    // 0..127
  int t = threadIdx.x;
  int q = t >> 2, dvb4 = (t & 3)*32;
  float z = 0.f;
  #pragma unroll
  for (int s=0;s<ZSPLIT;s++) z += zpart[(size_t)s*SQ + tile*64 + q];
  float vinv = 1.0f / z;
  const float* src = Vp + (size_t)(tile*64 + q)*DD + dvb4;
  #pragma unroll
  for (int j=0;j<8;j++){
    float4 f = ((const float4*)src)[j];
    vl[q][dvb4 + j*4 + 0] = f2bf(f.x*vinv);
    vl[q][dvb4 + j*4 + 1] = f2bf(f.y*vinv);
    vl[q][dvb4 + j*4 + 2] = f2bf(f.z*vinv);
    vl[q][dvb4 + j*4 + 3] = f2bf(f.w*vinv);
  }
  __syncthreads();
  char* obase = (char*)vst + (size_t)tile*16384;
  #pragma unroll
  for (int s2=0;s2<4;s2++){
    int sid = t*4 + s2;                 // 0..1023 = rec*64 + lane
    int rec = sid >> 6, lr = sid & 63;
    int dv = (rec & 7)*16 + (lr & 15);
    int qb = (rec >> 3)*32 + (lr >> 4)*8;
    unsigned int wv[4];
    #pragma unroll
    for (int p=0;p<4;p++){
      unsigned lo = vl[qb + p*2 + 0][dv];
      unsigned hi = vl[qb + p*2 + 1][dv];
      wv[p] = lo | (hi << 16);
    }
    ((uint4*)(obase + rec*1024 + lr*16))[0] = make_uint4(wv[0],wv[1],wv[2],wv[3]);
  }
}

// ---------------------------------------------------------------------------
// ko: HIGH-OCCUPANCY slim-wave pass. 256-thr blocks (4 waves, kg=0..3),
// wave owns 32 k-rows: kf[2][4] from global K stream, acc[2][8]=64 regs
// -> ~155 total regs, launch_bounds(256,3) => 3 waves/SIMD (vs 2 at r15's
// 256-reg waves). Grid = 64 kb x QSPL qsp (QSPL=16 -> 1024 blocks, 4/CU).
// Q: LDS double-buffer 2x16KB, 1 barrier/iter. V: read DIRECTLY from the
// global stream (coalesced 1KB records, L1-deduped across the 4 kg waves)
// -> V off the LDS pipe onto the parallel L1/TA pipe.
// Epilogue: plain per-wave stores into partial slice [qsp] (deterministic);
// atomic fallback when part==null.
// ---------------------------------------------------------------------------
__global__ __launch_bounds__(256, 3) void ko(const ushort_t* __restrict__ kst,
                                             const ushort_t* __restrict__ qst,
                                             const ushort_t* __restrict__ vst,
                                             float* __restrict__ part,
                                             float* __restrict__ out,
                                             int nqt){
  __shared__ __align__(16) char smem[32768];   // Q dbuf 2 x 16KB
  int wg = blockIdx.x;             // 64 * qspl
  int kb  = wg & 63;               // 0..63: k-rows kb*128..kb*128+127
  int qsp = wg >> 6;               // 0..qspl-1
  int t = threadIdx.x, lane = t & 63, kg = t >> 6;   // kg in 0..3
  int r15 = lane & 15, g4 = lane >> 4;

  // kf[kbk][kk]: wave's 32 k-rows from global K stream (one-time, coalesced)
  short8 kf[2][4];
  { const char* kbp = (const char*)kst + (size_t)(kb*2 + (kg>>1))*16384;
    int rg0 = (kg & 1)*2;
    #pragma unroll
    for (int b=0;b<2;b++)
      #pragma unroll
      for (int kk=0;kk<4;kk++)
        kf[b][kk] = *(const short8*)(kbp + (((rg0+b)*4+kk)<<10) + lane*16);
  }
  // stage Q(qtile 0) into buf0
  int qt0 = qsp*nqt;
  { const char* qg = (const char*)qst + (size_t)qt0*16384;
    #pragma unroll
    for (int i=0;i<4;i++)
      gld16(qg + (t + i*256)*16, smem + (t + i*256)*16);
  }

  f32x4 zero = {0.f,0.f,0.f,0.f};
  f32x4 acc[2][8];
  #pragma unroll
  for (int b=0;b<2;b++)
    #pragma unroll
    for (int i=0;i<8;i++) acc[b][i] = zero;

  const char* vgbase = (const char*)vst + (size_t)qt0*16384;

  for (int it=0; it<nqt; ++it){
    __syncthreads();                 // buf(it) DMA drained; buf(it^1) free
    const char* Qb = smem + (it&1)*16384;
    if (it+1 < nqt){
      const char* qg = (const char*)qst + (size_t)(qt0+it+1)*16384;
      char* dst = smem + ((it+1)&1)*16384;
      #pragma unroll
      for (int i=0;i<4;i++)
        gld16(qg + (t + i*256)*16, dst + (t + i*256)*16);
    }
    const char* vg = vgbase + (size_t)it*16384;
    #pragma unroll
    for (int qc=0; qc<2; ++qc){
      // ---- G1: S^T for wave's 32 k-rows x this 32-q chunk ----
      unsigned pw[2][4];             // [kbk][word]
      #pragma unroll
      for (int blk=0; blk<2; ++blk){
        f32x4 s0 = zero, s1 = zero;
        #pragma unroll
        for (int kk=0; kk<4; ++kk){
          short8 aq = *(const short8*)(Qb + (((qc*2+blk)*4+kk)<<10) + lane*16);
          s0 = __builtin_amdgcn_mfma_f32_16x16x32_bf16(aq, kf[0][kk], s0, 0, 0, 0);
          s1 = __builtin_amdgcn_mfma_f32_16x16x32_bf16(aq, kf[1][kk], s1, 0, 0, 0);
        }
        #pragma unroll
        for (int b=0;b<2;b++){
          f32x4 s = b ? s1 : s0;
          float p0 = __builtin_exp2f(s[0]);
          float p1 = __builtin_exp2f(s[1]);
          float p2 = __builtin_exp2f(s[2]);
          float p3 = __builtin_exp2f(s[3]);
          unsigned wa, wb;
          asm("v_cvt_pk_bf16_f32 %0, %1, %2" : "=v"(wa) : "v"(p0), "v"(p1));
          asm("v_cvt_pk_bf16_f32 %0, %1, %2" : "=v"(wb) : "v"(p2), "v"(p3));
          pw[b][blk*2+0] = wa;
          pw[b][blk*2+1] = wb;
        }
      }
      short8 af[2];
      #pragma unroll
      for (int b=0;b<2;b++){
        asm("v_permlane32_swap_b32 %0, %1" : "+v"(pw[b][0]), "+v"(pw[b][2]));
        asm("v_permlane32_swap_b32 %0, %1" : "+v"(pw[b][1]), "+v"(pw[b][3]));
        asm("v_permlane16_swap_b32 %0, %1" : "+v"(pw[b][0]), "+v"(pw[b][2]));
        asm("v_permlane16_swap_b32 %0, %1" : "+v"(pw[b][1]), "+v"(pw[b][3]));
        uint4v fw = { pw[b][0], pw[b][1], pw[b][2], pw[b][3] };
        af[b] = __builtin_bit_cast(short8, fw);
      }
      // ---- PV: V records straight from global (L1-hot, coalesced) ----
      __builtin_amdgcn_s_setprio(1);
      #pragma unroll
      for (int dvb=0; dvb<8; ++dvb){
        short8 bv = *(const short8*)(vg + ((qc*8+dvb)<<10) + lane*16);
        acc[0][dvb] = __builtin_amdgcn_mfma_f32_16x16x32_bf16(af[0], bv, acc[0][dvb], 0, 0, 0);
        acc[1][dvb] = __builtin_amdgcn_mfma_f32_16x16x32_bf16(af[1], bv, acc[1][dvb], 0, 0, 0);
      }
      __builtin_amdgcn_s_setprio(0);
    }
  }
  // ---- epilogue: plain stores into partial slice [qsp] (or atomic) ----
  float* ps = part ? (part + (size_t)qsp*SK*DD) : (float*)0;
  #pragma unroll
  for (int b=0;b<2;b++)
    #pragma unroll
    for (int dvb=0; dvb<8; ++dvb)
      #pragma unroll
      for (int j=0;j<4;j++){
        int k  = kb*128 + kg*32 + b*16 + g4*4 + j;
        int dv = dvb*16 + r15;
        if (ps) ps[(size_t)k*DD + dv] = acc[b][dvb][j];
        else    atomicAdd(out + (size_t)k*DD + dv, acc[b][dvb][j]);
      }
}

// ---------------------------------------------------------------------------
// kred: out = sum of ns partial slices, fixed order (deterministic).
// ---------------------------------------------------------------------------
__global__ __launch_bounds__(256) void kred(const float* __restrict__ part,
                                            float* __restrict__ out, int ns){
  int i = blockIdx.x*256 + threadIdx.x;          // 0..262143
  const float4* p = (const float4*)part;
  float4 a = p[i];
  for (int s=1;s<ns;s++){
    float4 b = p[(size_t)s*262144 + i];
    a.x += b.x; a.y += b.y; a.z += b.z; a.w += b.w;
  }
  ((float4*)out)[i] = a;
}

extern "C" void kernel_launch(void* const* d_in, const int* in_sizes, int n_in,
                              void* d_out, int out_size, void* d_ws, size_t ws_size,
                              hipStream_t stream) {
  const float* Kp = (const float*)d_in[0];
  const float* Qp = (const float*)d_in[1];
  const float* Vp = (const float*)d_in[2];
  float* out = (float*)d_out;
  char* ws = (char*)d_ws;
  ushort_t* kst  = (ushort_t*)ws;
  ushort_t* qst  = (ushort_t*)(ws + ((size_t)2<<20));
  ushort_t* vst  = (ushort_t*)(ws + ((size_t)4<<20));
  float* zpart   = (float*)(ws + ((size_t)6<<20));
  // partials: qspl slices x 4MB at ws+8MB
  int qspl;
  if      (ws_size >= ((size_t)72<<20)) qspl = 16;   // 8 + 16*4 MB
  else if (ws_size >= ((size_t)40<<20)) qspl = 8;    // 8 + 8*4 MB
  else                                  qspl = 0;    // atomic fallback
  float* part = qspl ? (float*)(ws + ((size_t)8<<20)) : (float*)0;

  prep_kq<<<dim3(1024), dim3(256), 0, stream>>>(Kp, Qp, kst, qst);
  kz     <<<dim3(1024), dim3(256), 0, stream>>>(kst, qst, zpart);
  prep_v <<<dim3(128),  dim3(256), 0, stream>>>(Vp, zpart, vst);
  if (qspl){
    ko   <<<dim3(64*qspl), dim3(256), 0, stream>>>(kst, qst, vst, part, out, 128/qspl);
    kred <<<dim3(1024), dim3(256), 0, stream>>>(part, out, qspl);
  } else {
    hipMemsetAsync(d_out, 0, (size_t)SK*DD*sizeof(float), stream);
    ko   <<<dim3(64*8), dim3(256), 0, stream>>>(kst, qst, vst, (float*)0, out, 16);
  }
}

// Round 17
// 100.619 us; speedup vs baseline: 1.2520x; 1.2520x over previous
//
#include <hip/hip_runtime.h>

#define SK 8192
#define SQ 8192
#define DD 128
#define ZSPLIT 8

typedef __attribute__((ext_vector_type(8))) short short8;
typedef __attribute__((ext_vector_type(4))) float f32x4;
typedef __attribute__((ext_vector_type(4))) unsigned uint4v;
typedef unsigned short ushort_t;

// round-to-nearest-even f32 -> bf16
__device__ __forceinline__ unsigned short f2bf(float x){
  unsigned int u = __float_as_uint(x);
  u += 0x7FFFu + ((u >> 16) & 1u);
  return (unsigned short)(u >> 16);
}

// async global->LDS DMA, 16B/lane. LDS dest = uniform base + lane*16.
__device__ __forceinline__ void gld16(const void* g, void* l){
  __builtin_amdgcn_global_load_lds(
      (const __attribute__((address_space(1))) unsigned int*)g,
      (__attribute__((address_space(3))) unsigned int*)l, 16, 0, 0);
}

// ---------------------------------------------------------------------------
// STREAM LAYOUTS (fragment-record form; all reads are coalesced 1KB records)
// K/Q stream: per 64-row tile, 16 records of 1KB; rec = rg*4 + kk.
//   Lane l, byte pair j: element M[tile*64 + rg*16 + (l&15)][kk*32 + (l>>4)*8 + j]
// V stream: per 64-q tile, 16 records; rec = qc*8 + dvb. Lane l:
//   element V^T[dvb*16 + (l&15)][qc*32 + (l>>4)*8 + j]  (V^T pre-scaled 1/Z)
// ---------------------------------------------------------------------------

// prep_kq: cast K (pre-scaled by log2(e)/sqrt(128)) and Q to bf16 streams.
__global__ __launch_bounds__(256) void prep_kq(const float* __restrict__ Kp,
                                               const float* __restrict__ Qp,
                                               ushort_t* __restrict__ kst,
                                               ushort_t* __restrict__ qst){
  int g = blockIdx.x*256 + threadIdx.x;
  int arr = g >> 17;
  int s   = g & 131071;
  int row = s >> 4;
  int c16 = s & 15;            // 8-elem slot: d = c16*8..c16*8+7
  const float* src = (arr ? Qp : Kp) + row*DD + c16*8;
  const float scale = arr ? 1.0f : 0.12751743f;   // log2(e)/sqrt(128)
  float4 f0 = ((const float4*)src)[0];
  float4 f1 = ((const float4*)src)[1];
  unsigned int wv[4];
  wv[0] = (unsigned)f2bf(f0.x*scale) | ((unsigned)f2bf(f0.y*scale) << 16);
  wv[1] = (unsigned)f2bf(f0.z*scale) | ((unsigned)f2bf(f0.w*scale) << 16);
  wv[2] = (unsigned)f2bf(f1.x*scale) | ((unsigned)f2bf(f1.y*scale) << 16);
  wv[3] = (unsigned)f2bf(f1.z*scale) | ((unsigned)f2bf(f1.w*scale) << 16);
  ushort_t* base = arr ? qst : kst;
  int tile = row >> 6, rg = (row >> 4) & 3, r15 = row & 15;
  int kk = c16 >> 2, g4 = c16 & 3;
  char* dst = (char*)base + (size_t)tile*16384 + (rg*4 + kk)*1024 + (g4*16 + r15)*16;
  ((uint4*)dst)[0] = make_uint4(wv[0],wv[1],wv[2],wv[3]);
}

// ---------------------------------------------------------------------------
// kz: per-column stats, BARRIER-FREE main loop + 1-deep register prefetch
// of the next K records (hides the L2 latency chain).
// ---------------------------------------------------------------------------
__global__ __launch_bounds__(256, 4) void kz(const ushort_t* __restrict__ kst,
                                             const ushort_t* __restrict__ qst,
                                             float* __restrict__ zpart){
  __shared__ __align__(16) float zred[256];
  int wg = blockIdx.x;            // 1024
  int qs   = wg >> 3;             // 0..127 (64-q stripe)
  int kspl = wg & 7;
  int t = threadIdx.x, lane = t & 63, w = t >> 6;   // w in 0..3

  short8 qf[4][4];
  { const char* qg = (const char*)qst + (size_t)qs*16384;
    #pragma unroll
    for (int qg_=0; qg_<4; ++qg_)
      #pragma unroll
      for (int kk=0; kk<4; ++kk)
        qf[qg_][kk] = *(const short8*)(qg + ((qg_*4+kk)<<10) + lane*16);
  }

  float zac0=0.f, zac1=0.f, zac2=0.f, zac3=0.f;
  const char* kbase = (const char*)kst + (size_t)(kspl*16)*16384 + ((w*4)<<10) + lane*16;
  short8 ak[4];
  #pragma unroll
  for (int kk=0;kk<4;kk++)
    ak[kk] = *(const short8*)(kbase + (kk<<10));
  for (int it=0; it<16; ++it){
    // prefetch next tile's records (redundant re-load on the last iter)
    int nit = (it+1 < 16) ? it+1 : 15;
    short8 nk[4];
    #pragma unroll
    for (int kk=0;kk<4;kk++)
      nk[kk] = *(const short8*)(kbase + (size_t)nit*16384 + (kk<<10));
    f32x4 s0={0,0,0,0}, s1={0,0,0,0}, s2={0,0,0,0}, s3={0,0,0,0};
    #pragma unroll
    for (int kk=0; kk<4; ++kk){
      s0 = __builtin_amdgcn_mfma_f32_16x16x32_bf16(ak[kk], qf[0][kk], s0, 0, 0, 0);
      s1 = __builtin_amdgcn_mfma_f32_16x16x32_bf16(ak[kk], qf[1][kk], s1, 0, 0, 0);
      s2 = __builtin_amdgcn_mfma_f32_16x16x32_bf16(ak[kk], qf[2][kk], s2, 0, 0, 0);
      s3 = __builtin_amdgcn_mfma_f32_16x16x32_bf16(ak[kk], qf[3][kk], s3, 0, 0, 0);
    }
    #pragma unroll
    for (int j=0;j<4;j++){
      zac0 += __builtin_exp2f(s0[j]);
      zac1 += __builtin_exp2f(s1[j]);
      zac2 += __builtin_exp2f(s2[j]);
      zac3 += __builtin_exp2f(s3[j]);
    }
    #pragma unroll
    for (int kk=0;kk<4;kk++) ak[kk] = nk[kk];
  }
  zac0 += __shfl_xor(zac0,16); zac0 += __shfl_xor(zac0,32);
  zac1 += __shfl_xor(zac1,16); zac1 += __shfl_xor(zac1,32);
  zac2 += __shfl_xor(zac2,16); zac2 += __shfl_xor(zac2,32);
  zac3 += __shfl_xor(zac3,16); zac3 += __shfl_xor(zac3,32);
  if (lane < 16){
    zred[w*64 + 0*16 + lane] = zac0;
    zred[w*64 + 1*16 + lane] = zac1;
    zred[w*64 + 2*16 + lane] = zac2;
    zred[w*64 + 3*16 + lane] = zac3;
  }
  __syncthreads();
  if (t < 64){
    float z = zred[t] + zred[64+t] + zred[128+t] + zred[192+t];
    zpart[(size_t)kspl*SQ + qs*64 + t] = z;
  }
}

// ---------------------------------------------------------------------------
// prep_v: runs AFTER kz. Vt[q,:] = V[q,:] / Z_q, written as V stream records.
// ---------------------------------------------------------------------------
__global__ __launch_bounds__(256) void prep_v(const float* __restrict__ Vp,
                                              const float* __restrict__ zpart,
                                              ushort_t* __restrict__ vst){
  __shared__ ushort_t vl[64][132];
  int tile = blockIdx.x;    // 0..127
  int t = threadIdx.x;
  int q = t >> 2, dvb4 = (t & 3)*32;
  float z = 0.f;
  #pragma unroll
  for (int s=0;s<ZSPLIT;s++) z += zpart[(size_t)s*SQ + tile*64 + q];
  float vinv = 1.0f / z;
  const float* src = Vp + (size_t)(tile*64 + q)*DD + dvb4;
  #pragma unroll
  for (int j=0;j<8;j++){
    float4 f = ((const float4*)src)[j];
    vl[q][dvb4 + j*4 + 0] = f2bf(f.x*vinv);
    vl[q][dvb4 + j*4 + 1] = f2bf(f.y*vinv);
    vl[q][dvb4 + j*4 + 2] = f2bf(f.z*vinv);
    vl[q][dvb4 + j*4 + 3] = f2bf(f.w*vinv);
  }
  __syncthreads();
  char* obase = (char*)vst + (size_t)tile*16384;
  #pragma unroll
  for (int s2=0;s2<4;s2++){
    int sid = t*4 + s2;                 // 0..1023 = rec*64 + lane
    int rec = sid >> 6, lr = sid & 63;
    int dv = (rec & 7)*16 + (lr & 15);
    int qb = (rec >> 3)*32 + (lr >> 4)*8;
    unsigned int wv[4];
    #pragma unroll
    for (int p=0;p<4;p++){
      unsigned lo = vl[qb + p*2 + 0][dv];
      unsigned hi = vl[qb + p*2 + 1][dv];
      wv[p] = lo | (hi << 16);
    }
    ((uint4*)(obase + rec*1024 + lr*16))[0] = make_uint4(wv[0],wv[1],wv[2],wv[3]);
  }
}

// ---------------------------------------------------------------------------
// ko: r15 compute (proven 47.6us) + split-K fixup epilogue: after plain
// stores into partial slice [qsp], the LAST of the 8 qsp-WGs per kt2
// (device-scope counter + threadfence release/acquire) sums the 8 slices
// of its 256k x 128dv region IN FIXED ASCENDING ORDER (bit-identical to
// the old kred) and writes `out`. Overlaps the reduction with ko's tail.
// Atomic fallback when part==null.
// ---------------------------------------------------------------------------
__global__ __launch_bounds__(512, 1) void ko(const ushort_t* __restrict__ kst,
                                             const ushort_t* __restrict__ qst,
                                             const ushort_t* __restrict__ vst,
                                             float* __restrict__ part,
                                             unsigned int* __restrict__ cnt,
                                             float* __restrict__ out){
  __shared__ __align__(16) char smem[131072];  // dbuf 2 x 64KB (2 q-tiles each)
  int wg = blockIdx.x;            // 256
  int kt2 = wg & 31;              // 0..31 (256 k-rows); xcd = kt2%8
  int qsp = wg >> 5;              // 0..7  (16 q-tiles of 64)
  int t = threadIdx.x, lane = t & 63, w = t >> 6;   // w in 0..7
  int kg = w & 3, qh = w >> 2;
  int r15 = lane & 15, g4 = lane >> 4;

  // kf[kb][kk]: wave's 64 k-rows, one-time coalesced global reads
  short8 kf[4][4];
  { const char* kb = (const char*)kst + (size_t)(kt2*4 + kg)*16384;
    #pragma unroll
    for (int b=0;b<4;b++)
      #pragma unroll
      for (int kk=0;kk<4;kk++)
        kf[b][kk] = *(const short8*)(kb + ((b*4+kk)<<10) + lane*16);
  }
  // stage pair 0 (q-tiles 0,1) into buf0
  { const char* qg = (const char*)qst + (size_t)(qsp*16)*16384;
    const char* vg = (const char*)vst + (size_t)(qsp*16)*16384;
    #pragma unroll
    for (int j=0;j<2;j++)
      #pragma unroll
      for (int i=0;i<2;i++){
        gld16(qg + j*16384 + (t + i*512)*16, smem + j*32768 + (t + i*512)*16);
        gld16(vg + j*16384 + (t + i*512)*16, smem + j*32768 + 16384 + (t + i*512)*16);
      }
  }

  f32x4 zero = {0.f,0.f,0.f,0.f};
  f32x4 acc[4][8];
  #pragma unroll
  for (int b=0;b<4;b++)
    #pragma unroll
    for (int i=0;i<8;i++) acc[b][i] = zero;

  for (int sit=0; sit<8; ++sit){
    __syncthreads();                 // buf(sit) DMA drained; buf(sit^1) free
    const char* Buf = smem + (sit&1)*65536;
    if (sit+1 < 8){
      const char* qg = (const char*)qst + (size_t)(qsp*16 + (sit+1)*2)*16384;
      const char* vg = (const char*)vst + (size_t)(qsp*16 + (sit+1)*2)*16384;
      char* dst = smem + ((sit+1)&1)*65536;
      #pragma unroll
      for (int j=0;j<2;j++)
        #pragma unroll
        for (int i=0;i<2;i++){
          gld16(qg + j*16384 + (t + i*512)*16, dst + j*32768 + (t + i*512)*16);
          gld16(vg + j*16384 + (t + i*512)*16, dst + j*32768 + 16384 + (t + i*512)*16);
        }
    }
    #pragma unroll
    for (int j=0;j<2;j++){
      const char* Qb = Buf + j*32768;
      const char* Vb = Qb + 16384;
      // ---- G1: S^T for 4 k-blocks x wave's 32-q half ----
      unsigned pw[4][4];               // [kb][word]
      #pragma unroll
      for (int blk=0; blk<2; ++blk){
        f32x4 s[4];
        #pragma unroll
        for (int b=0;b<4;b++) s[b] = zero;
        #pragma unroll
        for (int kk=0; kk<4; ++kk){
          short8 aq = *(const short8*)(Qb + (((qh*2+blk)*4+kk)<<10) + lane*16);
          #pragma unroll
          for (int b=0;b<4;b++)
            s[b] = __builtin_amdgcn_mfma_f32_16x16x32_bf16(aq, kf[b][kk], s[b], 0, 0, 0);
        }
        #pragma unroll
        for (int b=0;b<4;b++){
          float p0 = __builtin_exp2f(s[b][0]);
          float p1 = __builtin_exp2f(s[b][1]);
          float p2 = __builtin_exp2f(s[b][2]);
          float p3 = __builtin_exp2f(s[b][3]);
          unsigned wa, wb;
          asm("v_cvt_pk_bf16_f32 %0, %1, %2" : "=v"(wa) : "v"(p0), "v"(p1));
          asm("v_cvt_pk_bf16_f32 %0, %1, %2" : "=v"(wb) : "v"(p2), "v"(p3));
          pw[b][blk*2+0] = wa;
          pw[b][blk*2+1] = wb;
        }
      }
      short8 af[4];
      #pragma unroll
      for (int b=0;b<4;b++){
        asm("v_permlane32_swap_b32 %0, %1" : "+v"(pw[b][0]), "+v"(pw[b][2]));
        asm("v_permlane32_swap_b32 %0, %1" : "+v"(pw[b][1]), "+v"(pw[b][3]));
        asm("v_permlane16_swap_b32 %0, %1" : "+v"(pw[b][0]), "+v"(pw[b][2]));
        asm("v_permlane16_swap_b32 %0, %1" : "+v"(pw[b][1]), "+v"(pw[b][3]));
        uint4v fw = { pw[b][0], pw[b][1], pw[b][2], pw[b][3] };
        af[b] = __builtin_bit_cast(short8, fw);
      }
      // ---- PV: each V record feeds all 4 k-blocks ----
      __builtin_amdgcn_s_setprio(1);
      #pragma unroll
      for (int dvb=0; dvb<8; ++dvb){
        short8 bv = *(const short8*)(Vb + ((qh*8+dvb)<<10) + lane*16);
        #pragma unroll
        for (int b=0;b<4;b++)
          acc[b][dvb] = __builtin_amdgcn_mfma_f32_16x16x32_bf16(af[b], bv, acc[b][dvb], 0, 0, 0);
      }
      __builtin_amdgcn_s_setprio(0);
    }
  }
  // ---- epilogue: deterministic qh-pair reduce via LDS (2 x 64KB passes),
  //      then plain stores into partial slice [qsp] (or atomic fallback) ----
  f32x4* red = (f32x4*)smem;         // [b2*8+dvb][kg*64+lane]
  float* ps = part ? (part + (size_t)qsp*SK*DD) : 0;
  #pragma unroll
  for (int pass=0; pass<2; ++pass){
    __syncthreads();                 // buffers/prev-pass reads complete
    if (qh == 1){
      #pragma unroll
      for (int b2=0;b2<2;b2++)
        #pragma unroll
        for (int dvb=0; dvb<8; ++dvb)
          red[((b2*8 + dvb)<<8) + kg*64 + lane] = acc[pass*2+b2][dvb];
    }
    __syncthreads();
    if (qh == 0){
      #pragma unroll
      for (int b2=0;b2<2;b2++)
        #pragma unroll
        for (int dvb=0; dvb<8; ++dvb){
          f32x4 o = red[((b2*8 + dvb)<<8) + kg*64 + lane];
          f32x4 a = acc[pass*2+b2][dvb];
          #pragma unroll
          for (int j=0;j<4;j++){
            int k  = kt2*256 + kg*64 + (pass*2+b2)*16 + g4*4 + j;
            int dv = dvb*16 + r15;
            if (ps) ps[(size_t)k*DD + dv] = a[j] + o[j];
            else    atomicAdd(out + (size_t)k*DD + dv, a[j] + o[j]);
          }
        }
    }
  }
  // ---- split-K fixup: last qsp-WG of this kt2 reduces the 8 slices ----
  if (ps){
    __syncthreads();                 // all stores above drained (vmcnt at barrier)
    volatile int* flag = (int*)smem;
    if (t == 0){
      __threadfence();               // release: partial stores visible device-wide
      unsigned int v = atomicAdd(cnt + kt2, 1u);
      *flag = (v == 7u) ? 1 : 0;
    }
    __syncthreads();
    if (*flag){
      __threadfence();               // acquire: see other WGs' partials
      size_t base4 = (size_t)kt2*8192;   // region in float4 units (256x128 f32)
      const float4* p0 = (const float4*)part;
      float4* o4 = (float4*)out;
      for (int i=t; i<8192; i+=512){
        float4 a = p0[base4 + i];
        #pragma unroll
        for (int s=1;s<8;s++){
          const float4* psl = (const float4*)(part + (size_t)s*SK*DD);
          float4 b = psl[base4 + i];
          a.x += b.x; a.y += b.y; a.z += b.z; a.w += b.w;
        }
        o4[base4 + i] = a;
      }
    }
  }
}

extern "C" void kernel_launch(void* const* d_in, const int* in_sizes, int n_in,
                              void* d_out, int out_size, void* d_ws, size_t ws_size,
                              hipStream_t stream) {
  const float* Kp = (const float*)d_in[0];
  const float* Qp = (const float*)d_in[1];
  const float* Vp = (const float*)d_in[2];
  float* out = (float*)d_out;
  char* ws = (char*)d_ws;
  ushort_t* kst  = (ushort_t*)ws;
  ushort_t* qst  = (ushort_t*)(ws + ((size_t)2<<20));
  ushort_t* vst  = (ushort_t*)(ws + ((size_t)4<<20));
  float* zpart   = (float*)(ws + ((size_t)6<<20));
  unsigned int* cnt = (unsigned int*)(ws + ((size_t)6<<20) + ((size_t)512<<10));
  // partials: 8 slices x 4MB at ws+8MB (needs ws_size >= 40MB)
  bool use_part = ws_size >= ((size_t)40<<20);
  float* part = use_part ? (float*)(ws + ((size_t)8<<20)) : (float*)0;

  prep_kq<<<dim3(1024), dim3(256), 0, stream>>>(Kp, Qp, kst, qst);
  kz     <<<dim3(1024), dim3(256), 0, stream>>>(kst, qst, zpart);
  prep_v <<<dim3(128),  dim3(256), 0, stream>>>(Vp, zpart, vst);
  if (use_part){
    hipMemsetAsync(cnt, 0, 32*sizeof(unsigned int), stream);
    ko   <<<dim3(256),  dim3(512), 0, stream>>>(kst, qst, vst, part, cnt, out);
  } else {
    hipMemsetAsync(d_out, 0, (size_t)SK*DD*sizeof(float), stream);
    ko   <<<dim3(256),  dim3(512), 0, stream>>>(kst, qst, vst, (float*)0, (unsigned int*)0, out);
  }
}

// Round 18
// 81.322 us; speedup vs baseline: 1.5491x; 1.2373x over previous
//
#include <hip/hip_runtime.h>

#define SK 8192
#define SQ 8192
#define DD 128
#define ZSPLIT 8

typedef __attribute__((ext_vector_type(8))) short short8;
typedef __attribute__((ext_vector_type(4))) float f32x4;
typedef __attribute__((ext_vector_type(4))) unsigned uint4v;
typedef unsigned short ushort_t;

// round-to-nearest-even f32 -> bf16
__device__ __forceinline__ unsigned short f2bf(float x){
  unsigned int u = __float_as_uint(x);
  u += 0x7FFFu + ((u >> 16) & 1u);
  return (unsigned short)(u >> 16);
}

// async global->LDS DMA, 16B/lane. LDS dest = uniform base + lane*16.
__device__ __forceinline__ void gld16(const void* g, void* l){
  __builtin_amdgcn_global_load_lds(
      (const __attribute__((address_space(1))) unsigned int*)g,
      (__attribute__((address_space(3))) unsigned int*)l, 16, 0, 0);
}

// ---------------------------------------------------------------------------
// STREAM LAYOUTS (fragment-record form; all reads are coalesced 1KB records)
// K/Q stream: per 64-row tile, 16 records of 1KB; rec = rg*4 + kk.
//   Lane l, byte pair j: element M[tile*64 + rg*16 + (l&15)][kk*32 + (l>>4)*8 + j]
// V stream: per 64-q tile, 16 records; rec = qc*8 + dvb. Lane l:
//   element V^T[dvb*16 + (l&15)][qc*32 + (l>>4)*8 + j]  (V^T pre-scaled 1/Z)
// ---------------------------------------------------------------------------

// prep_kq: cast K (pre-scaled by log2(e)/sqrt(128)) and Q to bf16 streams.
__global__ __launch_bounds__(256) void prep_kq(const float* __restrict__ Kp,
                                               const float* __restrict__ Qp,
                                               ushort_t* __restrict__ kst,
                                               ushort_t* __restrict__ qst){
  int g = blockIdx.x*256 + threadIdx.x;
  int arr = g >> 17;
  int s   = g & 131071;
  int row = s >> 4;
  int c16 = s & 15;            // 8-elem slot: d = c16*8..c16*8+7
  const float* src = (arr ? Qp : Kp) + row*DD + c16*8;
  const float scale = arr ? 1.0f : 0.12751743f;   // log2(e)/sqrt(128)
  float4 f0 = ((const float4*)src)[0];
  float4 f1 = ((const float4*)src)[1];
  unsigned int wv[4];
  wv[0] = (unsigned)f2bf(f0.x*scale) | ((unsigned)f2bf(f0.y*scale) << 16);
  wv[1] = (unsigned)f2bf(f0.z*scale) | ((unsigned)f2bf(f0.w*scale) << 16);
  wv[2] = (unsigned)f2bf(f1.x*scale) | ((unsigned)f2bf(f1.y*scale) << 16);
  wv[3] = (unsigned)f2bf(f1.z*scale) | ((unsigned)f2bf(f1.w*scale) << 16);
  ushort_t* base = arr ? qst : kst;
  int tile = row >> 6, rg = (row >> 4) & 3, r15 = row & 15;
  int kk = c16 >> 2, g4 = c16 & 3;
  char* dst = (char*)base + (size_t)tile*16384 + (rg*4 + kk)*1024 + (g4*16 + r15)*16;
  ((uint4*)dst)[0] = make_uint4(wv[0],wv[1],wv[2],wv[3]);
}

// ---------------------------------------------------------------------------
// kz: per-column stats, BARRIER-FREE main loop + 1-deep register prefetch
// of the next K records (r17 — ~1.4us gain, passing).
// ---------------------------------------------------------------------------
__global__ __launch_bounds__(256, 4) void kz(const ushort_t* __restrict__ kst,
                                             const ushort_t* __restrict__ qst,
                                             float* __restrict__ zpart){
  __shared__ __align__(16) float zred[256];
  int wg = blockIdx.x;            // 1024
  int qs   = wg >> 3;             // 0..127 (64-q stripe)
  int kspl = wg & 7;
  int t = threadIdx.x, lane = t & 63, w = t >> 6;   // w in 0..3

  short8 qf[4][4];
  { const char* qg = (const char*)qst + (size_t)qs*16384;
    #pragma unroll
    for (int qg_=0; qg_<4; ++qg_)
      #pragma unroll
      for (int kk=0; kk<4; ++kk)
        qf[qg_][kk] = *(const short8*)(qg + ((qg_*4+kk)<<10) + lane*16);
  }

  float zac0=0.f, zac1=0.f, zac2=0.f, zac3=0.f;
  const char* kbase = (const char*)kst + (size_t)(kspl*16)*16384 + ((w*4)<<10) + lane*16;
  short8 ak[4];
  #pragma unroll
  for (int kk=0;kk<4;kk++)
    ak[kk] = *(const short8*)(kbase + (kk<<10));
  for (int it=0; it<16; ++it){
    int nit = (it+1 < 16) ? it+1 : 15;
    short8 nk[4];
    #pragma unroll
    for (int kk=0;kk<4;kk++)
      nk[kk] = *(const short8*)(kbase + (size_t)nit*16384 + (kk<<10));
    f32x4 s0={0,0,0,0}, s1={0,0,0,0}, s2={0,0,0,0}, s3={0,0,0,0};
    #pragma unroll
    for (int kk=0; kk<4; ++kk){
      s0 = __builtin_amdgcn_mfma_f32_16x16x32_bf16(ak[kk], qf[0][kk], s0, 0, 0, 0);
      s1 = __builtin_amdgcn_mfma_f32_16x16x32_bf16(ak[kk], qf[1][kk], s1, 0, 0, 0);
      s2 = __builtin_amdgcn_mfma_f32_16x16x32_bf16(ak[kk], qf[2][kk], s2, 0, 0, 0);
      s3 = __builtin_amdgcn_mfma_f32_16x16x32_bf16(ak[kk], qf[3][kk], s3, 0, 0, 0);
    }
    #pragma unroll
    for (int j=0;j<4;j++){
      zac0 += __builtin_exp2f(s0[j]);
      zac1 += __builtin_exp2f(s1[j]);
      zac2 += __builtin_exp2f(s2[j]);
      zac3 += __builtin_exp2f(s3[j]);
    }
    #pragma unroll
    for (int kk=0;kk<4;kk++) ak[kk] = nk[kk];
  }
  zac0 += __shfl_xor(zac0,16); zac0 += __shfl_xor(zac0,32);
  zac1 += __shfl_xor(zac1,16); zac1 += __shfl_xor(zac1,32);
  zac2 += __shfl_xor(zac2,16); zac2 += __shfl_xor(zac2,32);
  zac3 += __shfl_xor(zac3,16); zac3 += __shfl_xor(zac3,32);
  if (lane < 16){
    zred[w*64 + 0*16 + lane] = zac0;
    zred[w*64 + 1*16 + lane] = zac1;
    zred[w*64 + 2*16 + lane] = zac2;
    zred[w*64 + 3*16 + lane] = zac3;
  }
  __syncthreads();
  if (t < 64){
    float z = zred[t] + zred[64+t] + zred[128+t] + zred[192+t];
    zpart[(size_t)kspl*SQ + qs*64 + t] = z;
  }
}

// ---------------------------------------------------------------------------
// prep_v: runs AFTER kz. Vt[q,:] = V[q,:] / Z_q, written as V stream records.
// ---------------------------------------------------------------------------
__global__ __launch_bounds__(256) void prep_v(const float* __restrict__ Vp,
                                              const float* __restrict__ zpart,
                                              ushort_t* __restrict__ vst){
  __shared__ ushort_t vl[64][132];
  int tile = blockIdx.x;    // 0..127
  int t = threadIdx.x;
  int q = t >> 2, dvb4 = (t & 3)*32;
  float z = 0.f;
  #pragma unroll
  for (int s=0;s<ZSPLIT;s++) z += zpart[(size_t)s*SQ + tile*64 + q];
  float vinv = 1.0f / z;
  const float* src = Vp + (size_t)(tile*64 + q)*DD + dvb4;
  #pragma unroll
  for (int j=0;j<8;j++){
    float4 f = ((const float4*)src)[j];
    vl[q][dvb4 + j*4 + 0] = f2bf(f.x*vinv);
    vl[q][dvb4 + j*4 + 1] = f2bf(f.y*vinv);
    vl[q][dvb4 + j*4 + 2] = f2bf(f.z*vinv);
    vl[q][dvb4 + j*4 + 3] = f2bf(f.w*vinv);
  }
  __syncthreads();
  char* obase = (char*)vst + (size_t)tile*16384;
  #pragma unroll
  for (int s2=0;s2<4;s2++){
    int sid = t*4 + s2;                 // 0..1023 = rec*64 + lane
    int rec = sid >> 6, lr = sid & 63;
    int dv = (rec & 7)*16 + (lr & 15);
    int qb = (rec >> 3)*32 + (lr >> 4)*8;
    unsigned int wv[4];
    #pragma unroll
    for (int p=0;p<4;p++){
      unsigned lo = vl[qb + p*2 + 0][dv];
      unsigned hi = vl[qb + p*2 + 1][dv];
      wv[p] = lo | (hi << 16);
    }
    ((uint4*)(obase + rec*1024 + lr*16))[0] = make_uint4(wv[0],wv[1],wv[2],wv[3]);
  }
}

// ---------------------------------------------------------------------------
// ko: r9's slim-wave high-occupancy shape ported to stream records + plain
// stores. 512 thr = 8 waves = 4 kg x 2 qh; wave owns 32 k-rows (kf[2][4]
// from global K stream, r16-verified load) vs its 32-q half. acc[2][8]=64
// + ~64 arch VGPR = 128/wave -> launch_bounds(512,4) pins 4 waves/SIMD
// (2 blocks/CU with 64KB LDS). Q+V double-buffered 2x32KB, 1 barrier/iter,
// 16 iters. Epilogue: qh-pair LDS reduce (deterministic, r9-verified) then
// qh=0 plain-stores into partial slice [qsp]; atomic fallback.
// Grid = 64 kb x 8 qsp = 512; wgid%8 = kb%8 -> qsp-mates share an XCD.
// ---------------------------------------------------------------------------
__global__ __launch_bounds__(512, 4) void ko(const ushort_t* __restrict__ kst,
                                             const ushort_t* __restrict__ qst,
                                             const ushort_t* __restrict__ vst,
                                             float* __restrict__ part,
                                             float* __restrict__ out){
  __shared__ __align__(16) char smem[65536];   // dbuf 2 x (Q 16K + V 16K)
  int wg = blockIdx.x;            // 512
  int kb  = wg & 63;              // 0..63 (128 k-rows); xcd = kb%8
  int qsp = wg >> 6;              // 0..7  (16 q-tiles of 64)
  int t = threadIdx.x, lane = t & 63, w = t >> 6;   // w in 0..7
  int kg = w & 3, qh = w >> 2;
  int r15 = lane & 15, g4 = lane >> 4;

  // kf[b][kk]: wave's 32 k-rows from global K stream (one-time, coalesced)
  short8 kf[2][4];
  { const char* kbp = (const char*)kst + (size_t)(kb*2 + (kg>>1))*16384;
    int rg0 = (kg & 1)*2;
    #pragma unroll
    for (int b=0;b<2;b++)
      #pragma unroll
      for (int kk=0;kk<4;kk++)
        kf[b][kk] = *(const short8*)(kbp + (((rg0+b)*4+kk)<<10) + lane*16);
  }
  // stage Q0/V0 into buf0
  { const char* qg = (const char*)qst + (size_t)(qsp*16)*16384;
    const char* vg = (const char*)vst + (size_t)(qsp*16)*16384;
    #pragma unroll
    for (int i=0;i<2;i++){
      gld16(qg + (t + i*512)*16, smem + (t + i*512)*16);
      gld16(vg + (t + i*512)*16, smem + 16384 + (t + i*512)*16);
    }
  }

  f32x4 zero = {0.f,0.f,0.f,0.f};
  f32x4 acc[2][8];
  #pragma unroll
  for (int b=0;b<2;b++)
    #pragma unroll
    for (int i=0;i<8;i++) acc[b][i] = zero;

  for (int it=0; it<16; ++it){
    __syncthreads();                 // buf(it) DMA drained; buf(it^1) free
    const char* Qb = smem + (it&1)*32768;
    const char* Vb = Qb + 16384;
    // prefetch next Q/V into other buffer (drained at next barrier)
    if (it+1 < 16){
      const char* qg = (const char*)qst + (size_t)(qsp*16+it+1)*16384;
      const char* vg = (const char*)vst + (size_t)(qsp*16+it+1)*16384;
      char* dst = smem + ((it+1)&1)*32768;
      #pragma unroll
      for (int i=0;i<2;i++){
        gld16(qg + (t + i*512)*16, dst + (t + i*512)*16);
        gld16(vg + (t + i*512)*16, dst + 16384 + (t + i*512)*16);
      }
    }
    // ---- G1: S^T for wave's 32 k-rows x its 32-q half ----
    unsigned pw[2][4];               // [b][word]
    #pragma unroll
    for (int blk=0; blk<2; ++blk){
      f32x4 s0 = zero, s1 = zero;
      #pragma unroll
      for (int kk=0; kk<4; ++kk){
        short8 aq = *(const short8*)(Qb + (((qh*2+blk)*4+kk)<<10) + lane*16);
        s0 = __builtin_amdgcn_mfma_f32_16x16x32_bf16(aq, kf[0][kk], s0, 0, 0, 0);
        s1 = __builtin_amdgcn_mfma_f32_16x16x32_bf16(aq, kf[1][kk], s1, 0, 0, 0);
      }
      #pragma unroll
      for (int b=0;b<2;b++){
        f32x4 s = b ? s1 : s0;
        float p0 = __builtin_exp2f(s[0]);
        float p1 = __builtin_exp2f(s[1]);
        float p2 = __builtin_exp2f(s[2]);
        float p3 = __builtin_exp2f(s[3]);
        unsigned wa, wb;
        asm("v_cvt_pk_bf16_f32 %0, %1, %2" : "=v"(wa) : "v"(p0), "v"(p1));
        asm("v_cvt_pk_bf16_f32 %0, %1, %2" : "=v"(wb) : "v"(p2), "v"(p3));
        pw[b][blk*2+0] = wa;
        pw[b][blk*2+1] = wb;
      }
    }
    short8 af[2];
    #pragma unroll
    for (int b=0;b<2;b++){
      asm("v_permlane32_swap_b32 %0, %1" : "+v"(pw[b][0]), "+v"(pw[b][2]));
      asm("v_permlane32_swap_b32 %0, %1" : "+v"(pw[b][1]), "+v"(pw[b][3]));
      asm("v_permlane16_swap_b32 %0, %1" : "+v"(pw[b][0]), "+v"(pw[b][2]));
      asm("v_permlane16_swap_b32 %0, %1" : "+v"(pw[b][1]), "+v"(pw[b][3]));
      uint4v fw = { pw[b][0], pw[b][1], pw[b][2], pw[b][3] };
      af[b] = __builtin_bit_cast(short8, fw);
    }
    // ---- PV: O += P~.V~ for wave's q-half ----
    __builtin_amdgcn_s_setprio(1);
    #pragma unroll
    for (int dvb=0; dvb<8; ++dvb){
      short8 bv = *(const short8*)(Vb + ((qh*8+dvb)<<10) + lane*16);
      acc[0][dvb] = __builtin_amdgcn_mfma_f32_16x16x32_bf16(af[0], bv, acc[0][dvb], 0, 0, 0);
      acc[1][dvb] = __builtin_amdgcn_mfma_f32_16x16x32_bf16(af[1], bv, acc[1][dvb], 0, 0, 0);
    }
    __builtin_amdgcn_s_setprio(0);
  }
  // ---- epilogue: qh-pair reduce via LDS (one 64KB pass, deterministic),
  //      then qh=0 plain-stores into partial slice [qsp] (or atomic) ----
  __syncthreads();                   // all waves done with buffers
  f32x4* red = (f32x4*)smem;         // [b*8+dvb][kg*64+lane]
  if (qh == 1){
    #pragma unroll
    for (int b=0;b<2;b++)
      #pragma unroll
      for (int dvb=0; dvb<8; ++dvb)
        red[((b*8 + dvb)<<8) + kg*64 + lane] = acc[b][dvb];
  }
  __syncthreads();
  if (qh == 0){
    float* ps = part ? (part + (size_t)qsp*SK*DD) : (float*)0;
    #pragma unroll
    for (int b=0;b<2;b++)
      #pragma unroll
      for (int dvb=0; dvb<8; ++dvb){
        f32x4 o = red[((b*8 + dvb)<<8) + kg*64 + lane];
        f32x4 a = acc[b][dvb];
        #pragma unroll
        for (int j=0;j<4;j++){
          int k  = kb*128 + kg*32 + b*16 + g4*4 + j;
          int dv = dvb*16 + r15;
          if (ps) ps[(size_t)k*DD + dv] = a[j] + o[j];
          else    atomicAdd(out + (size_t)k*DD + dv, a[j] + o[j]);
        }
      }
  }
}

// ---------------------------------------------------------------------------
// kred: out = sum of 8 partial slices, fixed order (deterministic).
// ---------------------------------------------------------------------------
__global__ __launch_bounds__(256) void kred(const float* __restrict__ part,
                                            float* __restrict__ out){
  int i = blockIdx.x*256 + threadIdx.x;          // 0..262143
  const float4* p = (const float4*)part;
  float4 a = p[i];
  #pragma unroll
  for (int s=1;s<8;s++){
    float4 b = p[(size_t)s*262144 + i];
    a.x += b.x; a.y += b.y; a.z += b.z; a.w += b.w;
  }
  ((float4*)out)[i] = a;
}

extern "C" void kernel_launch(void* const* d_in, const int* in_sizes, int n_in,
                              void* d_out, int out_size, void* d_ws, size_t ws_size,
                              hipStream_t stream) {
  const float* Kp = (const float*)d_in[0];
  const float* Qp = (const float*)d_in[1];
  const float* Vp = (const float*)d_in[2];
  float* out = (float*)d_out;
  char* ws = (char*)d_ws;
  ushort_t* kst  = (ushort_t*)ws;
  ushort_t* qst  = (ushort_t*)(ws + ((size_t)2<<20));
  ushort_t* vst  = (ushort_t*)(ws + ((size_t)4<<20));
  float* zpart   = (float*)(ws + ((size_t)6<<20));
  // partials: 8 slices x 4MB at ws+8MB (needs ws_size >= 40MB)
  bool use_part = ws_size >= ((size_t)40<<20);
  float* part = use_part ? (float*)(ws + ((size_t)8<<20)) : (float*)0;

  prep_kq<<<dim3(1024), dim3(256), 0, stream>>>(Kp, Qp, kst, qst);
  kz     <<<dim3(1024), dim3(256), 0, stream>>>(kst, qst, zpart);
  prep_v <<<dim3(128),  dim3(256), 0, stream>>>(Vp, zpart, vst);
  if (use_part){
    ko   <<<dim3(512),  dim3(512), 0, stream>>>(kst, qst, vst, part, out);
    kred <<<dim3(1024), dim3(256), 0, stream>>>(part, out);
  } else {
    hipMemsetAsync(d_out, 0, (size_t)SK*DD*sizeof(float), stream);
    ko   <<<dim3(512),  dim3(512), 0, stream>>>(kst, qst, vst, (float*)0, out);
  }
}

// Round 19
// 79.231 us; speedup vs baseline: 1.5900x; 1.0264x over previous
//
#include <hip/hip_runtime.h>

#define SK 8192
#define SQ 8192
#define DD 128
#define ZSPLIT 8

typedef __attribute__((ext_vector_type(8))) short short8;
typedef __attribute__((ext_vector_type(4))) float f32x4;
typedef __attribute__((ext_vector_type(4))) unsigned uint4v;
typedef unsigned short ushort_t;

// round-to-nearest-even f32 -> bf16
__device__ __forceinline__ unsigned short f2bf(float x){
  unsigned int u = __float_as_uint(x);
  u += 0x7FFFu + ((u >> 16) & 1u);
  return (unsigned short)(u >> 16);
}

// async global->LDS DMA, 16B/lane. LDS dest = uniform base + lane*16.
__device__ __forceinline__ void gld16(const void* g, void* l){
  __builtin_amdgcn_global_load_lds(
      (const __attribute__((address_space(1))) unsigned int*)g,
      (__attribute__((address_space(3))) unsigned int*)l, 16, 0, 0);
}

// ---------------------------------------------------------------------------
// STREAM LAYOUTS (fragment-record form; all reads are coalesced 1KB records)
// K/Q stream: per 64-row tile, 16 records of 1KB; rec = rg*4 + kk.
//   Lane l, byte pair j: element M[tile*64 + rg*16 + (l&15)][kk*32 + (l>>4)*8 + j]
// V stream: per 64-q tile, 16 records; rec = qc*8 + dvb. Lane l:
//   element V^T[dvb*16 + (l&15)][qc*32 + (l>>4)*8 + j]  (V^T pre-scaled 1/Z)
// ---------------------------------------------------------------------------

// prep_kq: cast K (pre-scaled by log2(e)/sqrt(128)) and Q to bf16 streams.
__global__ __launch_bounds__(256) void prep_kq(const float* __restrict__ Kp,
                                               const float* __restrict__ Qp,
                                               ushort_t* __restrict__ kst,
                                               ushort_t* __restrict__ qst){
  int g = blockIdx.x*256 + threadIdx.x;
  int arr = g >> 17;
  int s   = g & 131071;
  int row = s >> 4;
  int c16 = s & 15;            // 8-elem slot: d = c16*8..c16*8+7
  const float* src = (arr ? Qp : Kp) + row*DD + c16*8;
  const float scale = arr ? 1.0f : 0.12751743f;   // log2(e)/sqrt(128)
  float4 f0 = ((const float4*)src)[0];
  float4 f1 = ((const float4*)src)[1];
  unsigned int wv[4];
  wv[0] = (unsigned)f2bf(f0.x*scale) | ((unsigned)f2bf(f0.y*scale) << 16);
  wv[1] = (unsigned)f2bf(f0.z*scale) | ((unsigned)f2bf(f0.w*scale) << 16);
  wv[2] = (unsigned)f2bf(f1.x*scale) | ((unsigned)f2bf(f1.y*scale) << 16);
  wv[3] = (unsigned)f2bf(f1.z*scale) | ((unsigned)f2bf(f1.w*scale) << 16);
  ushort_t* base = arr ? qst : kst;
  int tile = row >> 6, rg = (row >> 4) & 3, r15 = row & 15;
  int kk = c16 >> 2, g4 = c16 & 3;
  char* dst = (char*)base + (size_t)tile*16384 + (rg*4 + kk)*1024 + (g4*16 + r15)*16;
  ((uint4*)dst)[0] = make_uint4(wv[0],wv[1],wv[2],wv[3]);
}

// ---------------------------------------------------------------------------
// kz: per-column stats, BARRIER-FREE main loop + 1-deep register prefetch
// of the next K records (r17 — ~1.4us gain, passing). Unchanged from r18.
// ---------------------------------------------------------------------------
__global__ __launch_bounds__(256, 4) void kz(const ushort_t* __restrict__ kst,
                                             const ushort_t* __restrict__ qst,
                                             float* __restrict__ zpart){
  __shared__ __align__(16) float zred[256];
  int wg = blockIdx.x;            // 1024
  int qs   = wg >> 3;             // 0..127 (64-q stripe)
  int kspl = wg & 7;
  int t = threadIdx.x, lane = t & 63, w = t >> 6;   // w in 0..3

  short8 qf[4][4];
  { const char* qg = (const char*)qst + (size_t)qs*16384;
    #pragma unroll
    for (int qg_=0; qg_<4; ++qg_)
      #pragma unroll
      for (int kk=0; kk<4; ++kk)
        qf[qg_][kk] = *(const short8*)(qg + ((qg_*4+kk)<<10) + lane*16);
  }

  float zac0=0.f, zac1=0.f, zac2=0.f, zac3=0.f;
  const char* kbase = (const char*)kst + (size_t)(kspl*16)*16384 + ((w*4)<<10) + lane*16;
  short8 ak[4];
  #pragma unroll
  for (int kk=0;kk<4;kk++)
    ak[kk] = *(const short8*)(kbase + (kk<<10));
  for (int it=0; it<16; ++it){
    int nit = (it+1 < 16) ? it+1 : 15;
    short8 nk[4];
    #pragma unroll
    for (int kk=0;kk<4;kk++)
      nk[kk] = *(const short8*)(kbase + (size_t)nit*16384 + (kk<<10));
    f32x4 s0={0,0,0,0}, s1={0,0,0,0}, s2={0,0,0,0}, s3={0,0,0,0};
    #pragma unroll
    for (int kk=0; kk<4; ++kk){
      s0 = __builtin_amdgcn_mfma_f32_16x16x32_bf16(ak[kk], qf[0][kk], s0, 0, 0, 0);
      s1 = __builtin_amdgcn_mfma_f32_16x16x32_bf16(ak[kk], qf[1][kk], s1, 0, 0, 0);
      s2 = __builtin_amdgcn_mfma_f32_16x16x32_bf16(ak[kk], qf[2][kk], s2, 0, 0, 0);
      s3 = __builtin_amdgcn_mfma_f32_16x16x32_bf16(ak[kk], qf[3][kk], s3, 0, 0, 0);
    }
    #pragma unroll
    for (int j=0;j<4;j++){
      zac0 += __builtin_exp2f(s0[j]);
      zac1 += __builtin_exp2f(s1[j]);
      zac2 += __builtin_exp2f(s2[j]);
      zac3 += __builtin_exp2f(s3[j]);
    }
    #pragma unroll
    for (int kk=0;kk<4;kk++) ak[kk] = nk[kk];
  }
  zac0 += __shfl_xor(zac0,16); zac0 += __shfl_xor(zac0,32);
  zac1 += __shfl_xor(zac1,16); zac1 += __shfl_xor(zac1,32);
  zac2 += __shfl_xor(zac2,16); zac2 += __shfl_xor(zac2,32);
  zac3 += __shfl_xor(zac3,16); zac3 += __shfl_xor(zac3,32);
  if (lane < 16){
    zred[w*64 + 0*16 + lane] = zac0;
    zred[w*64 + 1*16 + lane] = zac1;
    zred[w*64 + 2*16 + lane] = zac2;
    zred[w*64 + 3*16 + lane] = zac3;
  }
  __syncthreads();
  if (t < 64){
    float z = zred[t] + zred[64+t] + zred[128+t] + zred[192+t];
    zpart[(size_t)kspl*SQ + qs*64 + t] = z;
  }
}

// ---------------------------------------------------------------------------
// prep_v: runs AFTER kz. Vt[q,:] = V[q,:] / Z_q, written as V stream records.
// ---------------------------------------------------------------------------
__global__ __launch_bounds__(256) void prep_v(const float* __restrict__ Vp,
                                              const float* __restrict__ zpart,
                                              ushort_t* __restrict__ vst){
  __shared__ ushort_t vl[64][132];
  int tile = blockIdx.x;    // 0..127
  int t = threadIdx.x;
  int q = t >> 2, dvb4 = (t & 3)*32;
  float z = 0.f;
  #pragma unroll
  for (int s=0;s<ZSPLIT;s++) z += zpart[(size_t)s*SQ + tile*64 + q];
  float vinv = 1.0f / z;
  const float* src = Vp + (size_t)(tile*64 + q)*DD + dvb4;
  #pragma unroll
  for (int j=0;j<8;j++){
    float4 f = ((const float4*)src)[j];
    vl[q][dvb4 + j*4 + 0] = f2bf(f.x*vinv);
    vl[q][dvb4 + j*4 + 1] = f2bf(f.y*vinv);
    vl[q][dvb4 + j*4 + 2] = f2bf(f.z*vinv);
    vl[q][dvb4 + j*4 + 3] = f2bf(f.w*vinv);
  }
  __syncthreads();
  char* obase = (char*)vst + (size_t)tile*16384;
  #pragma unroll
  for (int s2=0;s2<4;s2++){
    int sid = t*4 + s2;                 // 0..1023 = rec*64 + lane
    int rec = sid >> 6, lr = sid & 63;
    int dv = (rec & 7)*16 + (lr & 15);
    int qb = (rec >> 3)*32 + (lr >> 4)*8;
    unsigned int wv[4];
    #pragma unroll
    for (int p=0;p<4;p++){
      unsigned lo = vl[qb + p*2 + 0][dv];
      unsigned hi = vl[qb + p*2 + 1][dv];
      wv[p] = lo | (hi << 16);
    }
    ((uint4*)(obase + rec*1024 + lr*16))[0] = make_uint4(wv[0],wv[1],wv[2],wv[3]);
  }
}

// ---------------------------------------------------------------------------
// ko: r18 compute (proven 45us, 4 waves/SIMD), epilogue now stores partials
// as BF16 (halves partial-store and kred-read traffic; numerically safe:
// |partial| <~ 0.04, added err ~2e-4 vs 2e-3 threshold). Atomic fallback.
// ---------------------------------------------------------------------------
__global__ __launch_bounds__(512, 4) void ko(const ushort_t* __restrict__ kst,
                                             const ushort_t* __restrict__ qst,
                                             const ushort_t* __restrict__ vst,
                                             ushort_t* __restrict__ part,
                                             float* __restrict__ out){
  __shared__ __align__(16) char smem[65536];   // dbuf 2 x (Q 16K + V 16K)
  int wg = blockIdx.x;            // 512
  int kb  = wg & 63;              // 0..63 (128 k-rows); xcd = kb%8
  int qsp = wg >> 6;              // 0..7  (16 q-tiles of 64)
  int t = threadIdx.x, lane = t & 63, w = t >> 6;   // w in 0..7
  int kg = w & 3, qh = w >> 2;
  int r15 = lane & 15, g4 = lane >> 4;

  // kf[b][kk]: wave's 32 k-rows from global K stream (one-time, coalesced)
  short8 kf[2][4];
  { const char* kbp = (const char*)kst + (size_t)(kb*2 + (kg>>1))*16384;
    int rg0 = (kg & 1)*2;
    #pragma unroll
    for (int b=0;b<2;b++)
      #pragma unroll
      for (int kk=0;kk<4;kk++)
        kf[b][kk] = *(const short8*)(kbp + (((rg0+b)*4+kk)<<10) + lane*16);
  }
  // stage Q0/V0 into buf0
  { const char* qg = (const char*)qst + (size_t)(qsp*16)*16384;
    const char* vg = (const char*)vst + (size_t)(qsp*16)*16384;
    #pragma unroll
    for (int i=0;i<2;i++){
      gld16(qg + (t + i*512)*16, smem + (t + i*512)*16);
      gld16(vg + (t + i*512)*16, smem + 16384 + (t + i*512)*16);
    }
  }

  f32x4 zero = {0.f,0.f,0.f,0.f};
  f32x4 acc[2][8];
  #pragma unroll
  for (int b=0;b<2;b++)
    #pragma unroll
    for (int i=0;i<8;i++) acc[b][i] = zero;

  for (int it=0; it<16; ++it){
    __syncthreads();                 // buf(it) DMA drained; buf(it^1) free
    const char* Qb = smem + (it&1)*32768;
    const char* Vb = Qb + 16384;
    // prefetch next Q/V into other buffer (drained at next barrier)
    if (it+1 < 16){
      const char* qg = (const char*)qst + (size_t)(qsp*16+it+1)*16384;
      const char* vg = (const char*)vst + (size_t)(qsp*16+it+1)*16384;
      char* dst = smem + ((it+1)&1)*32768;
      #pragma unroll
      for (int i=0;i<2;i++){
        gld16(qg + (t + i*512)*16, dst + (t + i*512)*16);
        gld16(vg + (t + i*512)*16, dst + 16384 + (t + i*512)*16);
      }
    }
    // ---- G1: S^T for wave's 32 k-rows x its 32-q half ----
    unsigned pw[2][4];               // [b][word]
    #pragma unroll
    for (int blk=0; blk<2; ++blk){
      f32x4 s0 = zero, s1 = zero;
      #pragma unroll
      for (int kk=0; kk<4; ++kk){
        short8 aq = *(const short8*)(Qb + (((qh*2+blk)*4+kk)<<10) + lane*16);
        s0 = __builtin_amdgcn_mfma_f32_16x16x32_bf16(aq, kf[0][kk], s0, 0, 0, 0);
        s1 = __builtin_amdgcn_mfma_f32_16x16x32_bf16(aq, kf[1][kk], s1, 0, 0, 0);
      }
      #pragma unroll
      for (int b=0;b<2;b++){
        f32x4 s = b ? s1 : s0;
        float p0 = __builtin_exp2f(s[0]);
        float p1 = __builtin_exp2f(s[1]);
        float p2 = __builtin_exp2f(s[2]);
        float p3 = __builtin_exp2f(s[3]);
        unsigned wa, wb;
        asm("v_cvt_pk_bf16_f32 %0, %1, %2" : "=v"(wa) : "v"(p0), "v"(p1));
        asm("v_cvt_pk_bf16_f32 %0, %1, %2" : "=v"(wb) : "v"(p2), "v"(p3));
        pw[b][blk*2+0] = wa;
        pw[b][blk*2+1] = wb;
      }
    }
    short8 af[2];
    #pragma unroll
    for (int b=0;b<2;b++){
      asm("v_permlane32_swap_b32 %0, %1" : "+v"(pw[b][0]), "+v"(pw[b][2]));
      asm("v_permlane32_swap_b32 %0, %1" : "+v"(pw[b][1]), "+v"(pw[b][3]));
      asm("v_permlane16_swap_b32 %0, %1" : "+v"(pw[b][0]), "+v"(pw[b][2]));
      asm("v_permlane16_swap_b32 %0, %1" : "+v"(pw[b][1]), "+v"(pw[b][3]));
      uint4v fw = { pw[b][0], pw[b][1], pw[b][2], pw[b][3] };
      af[b] = __builtin_bit_cast(short8, fw);
    }
    // ---- PV: O += P~.V~ for wave's q-half ----
    __builtin_amdgcn_s_setprio(1);
    #pragma unroll
    for (int dvb=0; dvb<8; ++dvb){
      short8 bv = *(const short8*)(Vb + ((qh*8+dvb)<<10) + lane*16);
      acc[0][dvb] = __builtin_amdgcn_mfma_f32_16x16x32_bf16(af[0], bv, acc[0][dvb], 0, 0, 0);
      acc[1][dvb] = __builtin_amdgcn_mfma_f32_16x16x32_bf16(af[1], bv, acc[1][dvb], 0, 0, 0);
    }
    __builtin_amdgcn_s_setprio(0);
  }
  // ---- epilogue: qh-pair reduce via LDS (one 64KB pass, deterministic),
  //      then qh=0 stores BF16 partials into slice [qsp] (or atomic) ----
  __syncthreads();                   // all waves done with buffers
  f32x4* red = (f32x4*)smem;         // [b*8+dvb][kg*64+lane]
  if (qh == 1){
    #pragma unroll
    for (int b=0;b<2;b++)
      #pragma unroll
      for (int dvb=0; dvb<8; ++dvb)
        red[((b*8 + dvb)<<8) + kg*64 + lane] = acc[b][dvb];
  }
  __syncthreads();
  if (qh == 0){
    ushort_t* ps = part ? (part + (size_t)qsp*SK*DD) : (ushort_t*)0;
    #pragma unroll
    for (int b=0;b<2;b++)
      #pragma unroll
      for (int dvb=0; dvb<8; ++dvb){
        f32x4 o = red[((b*8 + dvb)<<8) + kg*64 + lane];
        f32x4 a = acc[b][dvb];
        #pragma unroll
        for (int j=0;j<4;j++){
          int k  = kb*128 + kg*32 + b*16 + g4*4 + j;
          int dv = dvb*16 + r15;
          if (ps) ps[(size_t)k*DD + dv] = f2bf(a[j] + o[j]);
          else    atomicAdd(out + (size_t)k*DD + dv, a[j] + o[j]);
        }
      }
  }
}

// ---------------------------------------------------------------------------
// kred: out = sum of 8 BF16 partial slices, fixed order (deterministic).
// 512 blocks x 256 thr; each thread: 8 elems (16B/slice reads, 32B write).
// ---------------------------------------------------------------------------
__global__ __launch_bounds__(256) void kred(const ushort_t* __restrict__ part,
                                            float* __restrict__ out){
  int i = blockIdx.x*256 + threadIdx.x;          // 0..131071
  const uint4* p = (const uint4*)part;           // 8 bf16 per uint4
  float a0=0,a1=0,a2=0,a3=0,a4=0,a5=0,a6=0,a7=0;
  #pragma unroll
  for (int s=0;s<8;s++){
    uint4 v = p[(size_t)s*131072 + i];
    a0 += __uint_as_float((v.x & 0xFFFFu) << 16);
    a1 += __uint_as_float(v.x & 0xFFFF0000u);
    a2 += __uint_as_float((v.y & 0xFFFFu) << 16);
    a3 += __uint_as_float(v.y & 0xFFFF0000u);
    a4 += __uint_as_float((v.z & 0xFFFFu) << 16);
    a5 += __uint_as_float(v.z & 0xFFFF0000u);
    a6 += __uint_as_float((v.w & 0xFFFFu) << 16);
    a7 += __uint_as_float(v.w & 0xFFFF0000u);
  }
  float4* o4 = (float4*)out;
  o4[(size_t)i*2 + 0] = make_float4(a0,a1,a2,a3);
  o4[(size_t)i*2 + 1] = make_float4(a4,a5,a6,a7);
}

extern "C" void kernel_launch(void* const* d_in, const int* in_sizes, int n_in,
                              void* d_out, int out_size, void* d_ws, size_t ws_size,
                              hipStream_t stream) {
  const float* Kp = (const float*)d_in[0];
  const float* Qp = (const float*)d_in[1];
  const float* Vp = (const float*)d_in[2];
  float* out = (float*)d_out;
  char* ws = (char*)d_ws;
  ushort_t* kst  = (ushort_t*)ws;
  ushort_t* qst  = (ushort_t*)(ws + ((size_t)2<<20));
  ushort_t* vst  = (ushort_t*)(ws + ((size_t)4<<20));
  float* zpart   = (float*)(ws + ((size_t)6<<20));
  // partials: 8 bf16 slices x 2MB at ws+8MB (16MB; gate kept at 40MB)
  bool use_part = ws_size >= ((size_t)40<<20);
  ushort_t* part = use_part ? (ushort_t*)(ws + ((size_t)8<<20)) : (ushort_t*)0;

  prep_kq<<<dim3(1024), dim3(256), 0, stream>>>(Kp, Qp, kst, qst);
  kz     <<<dim3(1024), dim3(256), 0, stream>>>(kst, qst, zpart);
  prep_v <<<dim3(128),  dim3(256), 0, stream>>>(Vp, zpart, vst);
  if (use_part){
    ko   <<<dim3(512),  dim3(512), 0, stream>>>(kst, qst, vst, part, out);
    kred <<<dim3(512),  dim3(256), 0, stream>>>(part, out);
  } else {
    hipMemsetAsync(d_out, 0, (size_t)SK*DD*sizeof(float), stream);
    ko   <<<dim3(512),  dim3(512), 0, stream>>>(kst, qst, vst, (ushort_t*)0, out);
  }
}

// Round 20
// 78.798 us; speedup vs baseline: 1.5987x; 1.0055x over previous
//
#include <hip/hip_runtime.h>

#define SK 8192
#define SQ 8192
#define DD 128
#define ZSPLIT 8

typedef __attribute__((ext_vector_type(8))) short short8;
typedef __attribute__((ext_vector_type(4))) float f32x4;
typedef __attribute__((ext_vector_type(4))) unsigned uint4v;
typedef unsigned short ushort_t;

// round-to-nearest-even f32 -> bf16
__device__ __forceinline__ unsigned short f2bf(float x){
  unsigned int u = __float_as_uint(x);
  u += 0x7FFFu + ((u >> 16) & 1u);
  return (unsigned short)(u >> 16);
}

// async global->LDS DMA, 16B/lane. LDS dest = uniform base + lane*16.
__device__ __forceinline__ void gld16(const void* g, void* l){
  __builtin_amdgcn_global_load_lds(
      (const __attribute__((address_space(1))) unsigned int*)g,
      (__attribute__((address_space(3))) unsigned int*)l, 16, 0, 0);
}

// ---------------------------------------------------------------------------
// STREAM LAYOUTS (fragment-record form; all reads are coalesced 1KB records)
// K/Q stream: per 64-row tile, 16 records of 1KB; rec = rg*4 + kk.
//   Lane l, byte pair j: element M[tile*64 + rg*16 + (l&15)][kk*32 + (l>>4)*8 + j]
// V stream: per 64-q tile, 16 records; rec = qc*8 + dvb. Lane l:
//   element V^T[dvb*16 + (l&15)][qc*32 + (l>>4)*8 + j]  (V^T pre-scaled 1/Z)
// ---------------------------------------------------------------------------

// prep_kq: cast K (pre-scaled by log2(e)/sqrt(128)) and Q to bf16 streams.
__global__ __launch_bounds__(256) void prep_kq(const float* __restrict__ Kp,
                                               const float* __restrict__ Qp,
                                               ushort_t* __restrict__ kst,
                                               ushort_t* __restrict__ qst){
  int g = blockIdx.x*256 + threadIdx.x;
  int arr = g >> 17;
  int s   = g & 131071;
  int row = s >> 4;
  int c16 = s & 15;            // 8-elem slot: d = c16*8..c16*8+7
  const float* src = (arr ? Qp : Kp) + row*DD + c16*8;
  const float scale = arr ? 1.0f : 0.12751743f;   // log2(e)/sqrt(128)
  float4 f0 = ((const float4*)src)[0];
  float4 f1 = ((const float4*)src)[1];
  unsigned int wv[4];
  wv[0] = (unsigned)f2bf(f0.x*scale) | ((unsigned)f2bf(f0.y*scale) << 16);
  wv[1] = (unsigned)f2bf(f0.z*scale) | ((unsigned)f2bf(f0.w*scale) << 16);
  wv[2] = (unsigned)f2bf(f1.x*scale) | ((unsigned)f2bf(f1.y*scale) << 16);
  wv[3] = (unsigned)f2bf(f1.z*scale) | ((unsigned)f2bf(f1.w*scale) << 16);
  ushort_t* base = arr ? qst : kst;
  int tile = row >> 6, rg = (row >> 4) & 3, r15 = row & 15;
  int kk = c16 >> 2, g4 = c16 & 3;
  char* dst = (char*)base + (size_t)tile*16384 + (rg*4 + kk)*1024 + (g4*16 + r15)*16;
  ((uint4*)dst)[0] = make_uint4(wv[0],wv[1],wv[2],wv[3]);
}

// ---------------------------------------------------------------------------
// kz: per-column stats, BARRIER-FREE main loop + 1-deep register prefetch
// of the next K records (r17/r19 — passing, unchanged).
// ---------------------------------------------------------------------------
__global__ __launch_bounds__(256, 4) void kz(const ushort_t* __restrict__ kst,
                                             const ushort_t* __restrict__ qst,
                                             float* __restrict__ zpart){
  __shared__ __align__(16) float zred[256];
  int wg = blockIdx.x;            // 1024
  int qs   = wg >> 3;             // 0..127 (64-q stripe)
  int kspl = wg & 7;
  int t = threadIdx.x, lane = t & 63, w = t >> 6;   // w in 0..3

  short8 qf[4][4];
  { const char* qg = (const char*)qst + (size_t)qs*16384;
    #pragma unroll
    for (int qg_=0; qg_<4; ++qg_)
      #pragma unroll
      for (int kk=0; kk<4; ++kk)
        qf[qg_][kk] = *(const short8*)(qg + ((qg_*4+kk)<<10) + lane*16);
  }

  float zac0=0.f, zac1=0.f, zac2=0.f, zac3=0.f;
  const char* kbase = (const char*)kst + (size_t)(kspl*16)*16384 + ((w*4)<<10) + lane*16;
  short8 ak[4];
  #pragma unroll
  for (int kk=0;kk<4;kk++)
    ak[kk] = *(const short8*)(kbase + (kk<<10));
  for (int it=0; it<16; ++it){
    int nit = (it+1 < 16) ? it+1 : 15;
    short8 nk[4];
    #pragma unroll
    for (int kk=0;kk<4;kk++)
      nk[kk] = *(const short8*)(kbase + (size_t)nit*16384 + (kk<<10));
    f32x4 s0={0,0,0,0}, s1={0,0,0,0}, s2={0,0,0,0}, s3={0,0,0,0};
    #pragma unroll
    for (int kk=0; kk<4; ++kk){
      s0 = __builtin_amdgcn_mfma_f32_16x16x32_bf16(ak[kk], qf[0][kk], s0, 0, 0, 0);
      s1 = __builtin_amdgcn_mfma_f32_16x16x32_bf16(ak[kk], qf[1][kk], s1, 0, 0, 0);
      s2 = __builtin_amdgcn_mfma_f32_16x16x32_bf16(ak[kk], qf[2][kk], s2, 0, 0, 0);
      s3 = __builtin_amdgcn_mfma_f32_16x16x32_bf16(ak[kk], qf[3][kk], s3, 0, 0, 0);
    }
    #pragma unroll
    for (int j=0;j<4;j++){
      zac0 += __builtin_exp2f(s0[j]);
      zac1 += __builtin_exp2f(s1[j]);
      zac2 += __builtin_exp2f(s2[j]);
      zac3 += __builtin_exp2f(s3[j]);
    }
    #pragma unroll
    for (int kk=0;kk<4;kk++) ak[kk] = nk[kk];
  }
  zac0 += __shfl_xor(zac0,16); zac0 += __shfl_xor(zac0,32);
  zac1 += __shfl_xor(zac1,16); zac1 += __shfl_xor(zac1,32);
  zac2 += __shfl_xor(zac2,16); zac2 += __shfl_xor(zac2,32);
  zac3 += __shfl_xor(zac3,16); zac3 += __shfl_xor(zac3,32);
  if (lane < 16){
    zred[w*64 + 0*16 + lane] = zac0;
    zred[w*64 + 1*16 + lane] = zac1;
    zred[w*64 + 2*16 + lane] = zac2;
    zred[w*64 + 3*16 + lane] = zac3;
  }
  __syncthreads();
  if (t < 64){
    float z = zred[t] + zred[64+t] + zred[128+t] + zred[192+t];
    zpart[(size_t)kspl*SQ + qs*64 + t] = z;
  }
}

// ---------------------------------------------------------------------------
// prep_v: runs AFTER kz. Vt[q,:] = V[q,:] / Z_q -> V stream records.
// Grid 256 = 128 tiles x 2 q-halves (record block qc*8..qc*8+7 depends only
// on q-half qc -> clean split, 2x parallelism vs r19's 128 WGs).
// ---------------------------------------------------------------------------
__global__ __launch_bounds__(256) void prep_v(const float* __restrict__ Vp,
                                              const float* __restrict__ zpart,
                                              ushort_t* __restrict__ vst){
  __shared__ ushort_t vl[32][132];
  int tile = blockIdx.x >> 1;     // 0..127
  int qc   = blockIdx.x & 1;      // q-half
  int t = threadIdx.x;
  int qr = t >> 3;                // 0..31 local q row
  int dvb16 = (t & 7)*16;         // dv chunk of 16
  int q = tile*64 + qc*32 + qr;
  float z = 0.f;
  #pragma unroll
  for (int s=0;s<ZSPLIT;s++) z += zpart[(size_t)s*SQ + q];
  float vinv = 1.0f / z;
  const float* src = Vp + (size_t)q*DD + dvb16;
  #pragma unroll
  for (int j=0;j<4;j++){
    float4 f = ((const float4*)src)[j];
    vl[qr][dvb16 + j*4 + 0] = f2bf(f.x*vinv);
    vl[qr][dvb16 + j*4 + 1] = f2bf(f.y*vinv);
    vl[qr][dvb16 + j*4 + 2] = f2bf(f.z*vinv);
    vl[qr][dvb16 + j*4 + 3] = f2bf(f.w*vinv);
  }
  __syncthreads();
  char* obase = (char*)vst + (size_t)tile*16384;
  #pragma unroll
  for (int s2=0;s2<2;s2++){
    int sid = t*2 + s2;                 // 0..511 = rec_local*64 + lane
    int recl = sid >> 6, lr = sid & 63;
    int dv = recl*16 + (lr & 15);       // recl = dvb (0..7)
    int qb = (lr >> 4)*8;               // local q base within half
    unsigned int wv[4];
    #pragma unroll
    for (int p=0;p<4;p++){
      unsigned lo = vl[qb + p*2 + 0][dv];
      unsigned hi = vl[qb + p*2 + 1][dv];
      wv[p] = lo | (hi << 16);
    }
    ((uint4*)(obase + (qc*8 + recl)*1024 + lr*16))[0] = make_uint4(wv[0],wv[1],wv[2],wv[3]);
  }
}

// ---------------------------------------------------------------------------
// ko: r18/r19 compute (proven 45us, 4 waves/SIMD); setprio(1) now wraps
// BOTH MFMA clusters (G1 + PV) — T5 coverage test. BF16 partial epilogue.
// ---------------------------------------------------------------------------
__global__ __launch_bounds__(512, 4) void ko(const ushort_t* __restrict__ kst,
                                             const ushort_t* __restrict__ qst,
                                             const ushort_t* __restrict__ vst,
                                             ushort_t* __restrict__ part,
                                             float* __restrict__ out){
  __shared__ __align__(16) char smem[65536];   // dbuf 2 x (Q 16K + V 16K)
  int wg = blockIdx.x;            // 512
  int kb  = wg & 63;              // 0..63 (128 k-rows); xcd = kb%8
  int qsp = wg >> 6;              // 0..7  (16 q-tiles of 64)
  int t = threadIdx.x, lane = t & 63, w = t >> 6;   // w in 0..7
  int kg = w & 3, qh = w >> 2;
  int r15 = lane & 15, g4 = lane >> 4;

  // kf[b][kk]: wave's 32 k-rows from global K stream (one-time, coalesced)
  short8 kf[2][4];
  { const char* kbp = (const char*)kst + (size_t)(kb*2 + (kg>>1))*16384;
    int rg0 = (kg & 1)*2;
    #pragma unroll
    for (int b=0;b<2;b++)
      #pragma unroll
      for (int kk=0;kk<4;kk++)
        kf[b][kk] = *(const short8*)(kbp + (((rg0+b)*4+kk)<<10) + lane*16);
  }
  // stage Q0/V0 into buf0
  { const char* qg = (const char*)qst + (size_t)(qsp*16)*16384;
    const char* vg = (const char*)vst + (size_t)(qsp*16)*16384;
    #pragma unroll
    for (int i=0;i<2;i++){
      gld16(qg + (t + i*512)*16, smem + (t + i*512)*16);
      gld16(vg + (t + i*512)*16, smem + 16384 + (t + i*512)*16);
    }
  }

  f32x4 zero = {0.f,0.f,0.f,0.f};
  f32x4 acc[2][8];
  #pragma unroll
  for (int b=0;b<2;b++)
    #pragma unroll
    for (int i=0;i<8;i++) acc[b][i] = zero;

  for (int it=0; it<16; ++it){
    __syncthreads();                 // buf(it) DMA drained; buf(it^1) free
    const char* Qb = smem + (it&1)*32768;
    const char* Vb = Qb + 16384;
    // prefetch next Q/V into other buffer (drained at next barrier)
    if (it+1 < 16){
      const char* qg = (const char*)qst + (size_t)(qsp*16+it+1)*16384;
      const char* vg = (const char*)vst + (size_t)(qsp*16+it+1)*16384;
      char* dst = smem + ((it+1)&1)*32768;
      #pragma unroll
      for (int i=0;i<2;i++){
        gld16(qg + (t + i*512)*16, dst + (t + i*512)*16);
        gld16(vg + (t + i*512)*16, dst + 16384 + (t + i*512)*16);
      }
    }
    // ---- G1: S^T for wave's 32 k-rows x its 32-q half ----
    unsigned pw[2][4];               // [b][word]
    #pragma unroll
    for (int blk=0; blk<2; ++blk){
      f32x4 s0 = zero, s1 = zero;
      __builtin_amdgcn_s_setprio(1);
      #pragma unroll
      for (int kk=0; kk<4; ++kk){
        short8 aq = *(const short8*)(Qb + (((qh*2+blk)*4+kk)<<10) + lane*16);
        s0 = __builtin_amdgcn_mfma_f32_16x16x32_bf16(aq, kf[0][kk], s0, 0, 0, 0);
        s1 = __builtin_amdgcn_mfma_f32_16x16x32_bf16(aq, kf[1][kk], s1, 0, 0, 0);
      }
      __builtin_amdgcn_s_setprio(0);
      #pragma unroll
      for (int b=0;b<2;b++){
        f32x4 s = b ? s1 : s0;
        float p0 = __builtin_exp2f(s[0]);
        float p1 = __builtin_exp2f(s[1]);
        float p2 = __builtin_exp2f(s[2]);
        float p3 = __builtin_exp2f(s[3]);
        unsigned wa, wb;
        asm("v_cvt_pk_bf16_f32 %0, %1, %2" : "=v"(wa) : "v"(p0), "v"(p1));
        asm("v_cvt_pk_bf16_f32 %0, %1, %2" : "=v"(wb) : "v"(p2), "v"(p3));
        pw[b][blk*2+0] = wa;
        pw[b][blk*2+1] = wb;
      }
    }
    short8 af[2];
    #pragma unroll
    for (int b=0;b<2;b++){
      asm("v_permlane32_swap_b32 %0, %1" : "+v"(pw[b][0]), "+v"(pw[b][2]));
      asm("v_permlane32_swap_b32 %0, %1" : "+v"(pw[b][1]), "+v"(pw[b][3]));
      asm("v_permlane16_swap_b32 %0, %1" : "+v"(pw[b][0]), "+v"(pw[b][2]));
      asm("v_permlane16_swap_b32 %0, %1" : "+v"(pw[b][1]), "+v"(pw[b][3]));
      uint4v fw = { pw[b][0], pw[b][1], pw[b][2], pw[b][3] };
      af[b] = __builtin_bit_cast(short8, fw);
    }
    // ---- PV: O += P~.V~ for wave's q-half ----
    __builtin_amdgcn_s_setprio(1);
    #pragma unroll
    for (int dvb=0; dvb<8; ++dvb){
      short8 bv = *(const short8*)(Vb + ((qh*8+dvb)<<10) + lane*16);
      acc[0][dvb] = __builtin_amdgcn_mfma_f32_16x16x32_bf16(af[0], bv, acc[0][dvb], 0, 0, 0);
      acc[1][dvb] = __builtin_amdgcn_mfma_f32_16x16x32_bf16(af[1], bv, acc[1][dvb], 0, 0, 0);
    }
    __builtin_amdgcn_s_setprio(0);
  }
  // ---- epilogue: qh-pair reduce via LDS (one 64KB pass, deterministic),
  //      then qh=0 stores BF16 partials into slice [qsp] (or atomic) ----
  __syncthreads();                   // all waves done with buffers
  f32x4* red = (f32x4*)smem;         // [b*8+dvb][kg*64+lane]
  if (qh == 1){
    #pragma unroll
    for (int b=0;b<2;b++)
      #pragma unroll
      for (int dvb=0; dvb<8; ++dvb)
        red[((b*8 + dvb)<<8) + kg*64 + lane] = acc[b][dvb];
  }
  __syncthreads();
  if (qh == 0){
    ushort_t* ps = part ? (part + (size_t)qsp*SK*DD) : (ushort_t*)0;
    #pragma unroll
    for (int b=0;b<2;b++)
      #pragma unroll
      for (int dvb=0; dvb<8; ++dvb){
        f32x4 o = red[((b*8 + dvb)<<8) + kg*64 + lane];
        f32x4 a = acc[b][dvb];
        #pragma unroll
        for (int j=0;j<4;j++){
          int k  = kb*128 + kg*32 + b*16 + g4*4 + j;
          int dv = dvb*16 + r15;
          if (ps) ps[(size_t)k*DD + dv] = f2bf(a[j] + o[j]);
          else    atomicAdd(out + (size_t)k*DD + dv, a[j] + o[j]);
        }
      }
  }
}

// ---------------------------------------------------------------------------
// kred: out = sum of 8 BF16 partial slices, fixed order (deterministic).
// ---------------------------------------------------------------------------
__global__ __launch_bounds__(256) void kred(const ushort_t* __restrict__ part,
                                            float* __restrict__ out){
  int i = blockIdx.x*256 + threadIdx.x;          // 0..131071
  const uint4* p = (const uint4*)part;           // 8 bf16 per uint4
  float a0=0,a1=0,a2=0,a3=0,a4=0,a5=0,a6=0,a7=0;
  #pragma unroll
  for (int s=0;s<8;s++){
    uint4 v = p[(size_t)s*131072 + i];
    a0 += __uint_as_float((v.x & 0xFFFFu) << 16);
    a1 += __uint_as_float(v.x & 0xFFFF0000u);
    a2 += __uint_as_float((v.y & 0xFFFFu) << 16);
    a3 += __uint_as_float(v.y & 0xFFFF0000u);
    a4 += __uint_as_float((v.z & 0xFFFFu) << 16);
    a5 += __uint_as_float(v.z & 0xFFFF0000u);
    a6 += __uint_as_float((v.w & 0xFFFFu) << 16);
    a7 += __uint_as_float(v.w & 0xFFFF0000u);
  }
  float4* o4 = (float4*)out;
  o4[(size_t)i*2 + 0] = make_float4(a0,a1,a2,a3);
  o4[(size_t)i*2 + 1] = make_float4(a4,a5,a6,a7);
}

extern "C" void kernel_launch(void* const* d_in, const int* in_sizes, int n_in,
                              void* d_out, int out_size, void* d_ws, size_t ws_size,
                              hipStream_t stream) {
  const float* Kp = (const float*)d_in[0];
  const float* Qp = (const float*)d_in[1];
  const float* Vp = (const float*)d_in[2];
  float* out = (float*)d_out;
  char* ws = (char*)d_ws;
  ushort_t* kst  = (ushort_t*)ws;
  ushort_t* qst  = (ushort_t*)(ws + ((size_t)2<<20));
  ushort_t* vst  = (ushort_t*)(ws + ((size_t)4<<20));
  float* zpart   = (float*)(ws + ((size_t)6<<20));
  // partials: 8 bf16 slices x 2MB at ws+8MB (16MB; gate kept at 40MB)
  bool use_part = ws_size >= ((size_t)40<<20);
  ushort_t* part = use_part ? (ushort_t*)(ws + ((size_t)8<<20)) : (ushort_t*)0;

  prep_kq<<<dim3(1024), dim3(256), 0, stream>>>(Kp, Qp, kst, qst);
  kz     <<<dim3(1024), dim3(256), 0, stream>>>(kst, qst, zpart);
  prep_v <<<dim3(256),  dim3(256), 0, stream>>>(Vp, zpart, vst);
  if (use_part){
    ko   <<<dim3(512),  dim3(512), 0, stream>>>(kst, qst, vst, part, out);
    kred <<<dim3(512),  dim3(256), 0, stream>>>(part, out);
  } else {
    hipMemsetAsync(d_out, 0, (size_t)SK*DD*sizeof(float), stream);
    ko   <<<dim3(512),  dim3(512), 0, stream>>>(kst, qst, vst, (ushort_t*)0, out);
  }
}